// Round 6
// baseline (589.849 us; speedup 1.0000x reference)
//
#include <hip/hip_runtime.h>
#include <hip/hip_cooperative_groups.h>

namespace cg = cooperative_groups;

#define ENC_NEGINF 0x007FFFFFu
#define NN_FINE 100000
#define NN_COARSE 1800
#define INV_N  (1.0f / 100000.0f)
#define INV_N2 (1.0f / 1800.0f)

__device__ __forceinline__ unsigned enc_f(float f) {
    unsigned u = __float_as_uint(f);
    return (u & 0x80000000u) ? ~u : (u | 0x80000000u);
}
__device__ __forceinline__ float dec_f(unsigned k) {
    return (k & 0x80000000u) ? __uint_as_float(k & 0x7fffffffu) : __uint_as_float(~k);
}

__device__ __forceinline__ float2 bn_ss(const float* __restrict__ st,
                                        const float* __restrict__ g,
                                        const float* __restrict__ be,
                                        int r, float invn) {
    float mu  = st[r] * invn;
    float var = fmaxf(st[128 + r] * invn - mu * mu, 0.f);
    float s = g[r] * rsqrtf(var + 1e-5f);
    return make_float2(s, be[r] - mu * s);
}

struct KArgs {
    const float *x, *pos;
    const int *e1, *e2;
    const float *wl1,*ws1,*wp1,*bp1,*g1,*be1;
    const float *wl2,*ws2,*wp2,*bp2,*g2,*be2;
    const float *wl3,*ws3,*wp3,*bp3,*g3,*be3;
    const float *wl4,*ws4,*wp4,*bp4,*g4,*be4;
    const float *wl5,*ws5,*wp5,*bp5,*g5,*be5;
    const float *wfc;
    float4 *SHPf; float2 *CAPf;
    float *Y1,*Y2,*Z1,*Y3,*STATS,*X2,*POS2;
    float4 *SHPc; float2 *CAPc;
    float *Y4,*Y5,*POOLED;
    unsigned *PK; float *PC,*PP;
    float *out;
};

// ---------------- phase A: node transform (grid-stride) ---------------------
// MODE 0: f=in. 1: f=bn(in), write zout=bn(in). 2: f=bn(in)+skipf.
template<int CIN, int COUT, int MODE>
__device__ void phase_a(int gtid, int gs, const float* __restrict__ in,
                        const float* __restrict__ st, const float* __restrict__ g,
                        const float* __restrict__ be, float invn,
                        const float* __restrict__ skipf,
                        const float* __restrict__ wl, const float* __restrict__ wsrc,
                        const float* __restrict__ wpos, const float* __restrict__ bpos,
                        const float* __restrict__ pos,
                        float4* __restrict__ SHP, float2* __restrict__ CAP,
                        float* __restrict__ zout, int NN) {
    constexpr int P = COUT / 2;
    for (int u = gtid; u < NN * P; u += gs) {
        int i = u / P, p = u % P;
        float f[CIN];
#pragma unroll
        for (int r = 0; r < CIN; ++r) {
            float v = in[i * CIN + r];
            if constexpr (MODE >= 1) {
                float2 ss = bn_ss(st, g, be, r, invn);
                v = v * ss.x + ss.y;
            }
            if constexpr (MODE == 2) v += skipf[i * CIN + r];
            f[r] = v;
        }
        int c0 = 2 * p;
        float h0 = 0.f, a0 = 0.f, h1 = 0.f, a1 = 0.f;
#pragma unroll
        for (int r = 0; r < CIN; ++r) {
            float2 wlr = *reinterpret_cast<const float2*>(&wl[r * COUT + c0]);
            float2 wsr = *reinterpret_cast<const float2*>(&wsrc[r * COUT + c0]);
            h0 += f[r] * wlr.x; h1 += f[r] * wlr.y;
            a0 += f[r] * wsr.x; a1 += f[r] * wsr.y;
        }
        float px = pos[i * 3], py = pos[i * 3 + 1], pz = pos[i * 3 + 2];
        float2 w0 = *reinterpret_cast<const float2*>(&wpos[c0]);
        float2 w1 = *reinterpret_cast<const float2*>(&wpos[COUT + c0]);
        float2 w2 = *reinterpret_cast<const float2*>(&wpos[2 * COUT + c0]);
        float pd0 = px * w0.x + py * w1.x + pz * w2.x;
        float pd1 = px * w0.y + py * w1.y + pz * w2.y;
        float2 bp = *reinterpret_cast<const float2*>(&bpos[c0]);
        SHP[(size_t)i * P + p] = make_float4(a0 + pd0, a1 + pd1, h0 - pd0, h1 - pd1);
        CAP[(size_t)i * P + p] = make_float2(pd0 + bp.x, pd1 + bp.y);
        if constexpr (MODE == 1) {
            float2 s0 = bn_ss(st, g, be, c0, invn);
            float2 s1 = bn_ss(st, g, be, c0 + 1, invn);
            float2 zv = make_float2(in[i * CIN + c0] * s0.x + s0.y,
                                    in[i * CIN + c0 + 1] * s1.x + s1.y);
            *reinterpret_cast<float2*>(&zout[i * CIN + c0]) = zv;
        }
    }
}

// ---------------- phase E: edge softmax + inline BN stats -------------------
template<int C, bool COARSE>
__device__ void phase_e(int tid, int gtid, int gs,
                        const float4* __restrict__ SHP, const float2* __restrict__ CAP,
                        const int* __restrict__ esrc, float2* __restrict__ y2,
                        float* __restrict__ stats, float* ldsf, int NN) {
    constexpr int P = C / 2;
    constexpr int DEG_ = COARSE ? 8 : 16;
    float* ls = ldsf;
    float* lq = ldsf + C;
    if (tid < C) { ls[tid] = 0.f; lq[tid] = 0.f; }
    __syncthreads();
    float sa0 = 0.f, sa1 = 0.f, sq0 = 0.f, sq1 = 0.f;
    for (int u = gtid; u < NN * P; u += gs) {   // gs % P == 0 -> p loop-invariant
        int i = u / P, p = u % P;
        int sidx[DEG_];
        if constexpr (!COARSE) {
            const int4* e4 = reinterpret_cast<const int4*>(esrc) + i * 4;
            int4 q0 = e4[0], q1 = e4[1], q2 = e4[2], q3 = e4[3];
            sidx[0] = q0.x;  sidx[1] = q0.y;  sidx[2]  = q0.z;  sidx[3]  = q0.w;
            sidx[4] = q1.x;  sidx[5] = q1.y;  sidx[6]  = q1.z;  sidx[7]  = q1.w;
            sidx[8] = q2.x;  sidx[9] = q2.y;  sidx[10] = q2.z;  sidx[11] = q2.w;
            sidx[12] = q3.x; sidx[13] = q3.y; sidx[14] = q3.z;  sidx[15] = q3.w;
        } else {
            int b = i / 225, j = i % 225;
#pragma unroll
            for (int e = 0; e < DEG_; ++e) sidx[e] = esrc[b * 1800 + e * 225 + j];
        }
        float4 q[DEG_ + 1];
#pragma unroll
        for (int e = 0; e < DEG_; ++e)
            q[e] = SHP[(size_t)sidx[e] * P + p];
        q[DEG_] = SHP[(size_t)i * P + p];

        float smin0 = q[0].x, smin1 = q[0].y;
#pragma unroll
        for (int e = 1; e <= DEG_; ++e) {
            smin0 = fminf(smin0, q[e].x);
            smin1 = fminf(smin1, q[e].y);
        }
        float den0 = 0.f, acc0 = 0.f, den1 = 0.f, acc1 = 0.f;
#pragma unroll
        for (int e = 0; e <= DEG_; ++e) {
            float ex0 = __expf(smin0 - q[e].x);
            float ex1 = __expf(smin1 - q[e].y);
            den0 += ex0; acc0 += ex0 * q[e].z;
            den1 += ex1; acc1 += ex1 * q[e].w;
        }
        float2 Ci = CAP[(size_t)i * P + p];
        float o0 = (acc0 + Ci.x * den0) / (den0 + 1e-16f);
        float o1 = (acc1 + Ci.y * den1) / (den1 + 1e-16f);
        float y0 = o0 > 0.f ? o0 : (__expf(o0) - 1.f);
        float y1 = o1 > 0.f ? o1 : (__expf(o1) - 1.f);
        y2[(size_t)i * P + p] = make_float2(y0, y1);
        sa0 += y0; sq0 += y0 * y0;
        sa1 += y1; sq1 += y1 * y1;
    }
    // wave reduce over lanes with same p (lane stride P)
#pragma unroll
    for (int m = P; m < 64; m <<= 1) {
        sa0 += __shfl_xor(sa0, m); sa1 += __shfl_xor(sa1, m);
        sq0 += __shfl_xor(sq0, m); sq1 += __shfl_xor(sq1, m);
    }
    int p_const = tid % P;      // == gtid % P (block start multiple of P)
    if ((tid & 63) < P) {
        int c0 = 2 * p_const;
        atomicAdd(&ls[c0], sa0);     atomicAdd(&ls[c0 + 1], sa1);
        atomicAdd(&lq[c0], sq0);     atomicAdd(&lq[c0 + 1], sq1);
    }
    __syncthreads();
    if (tid < C) {
        atomicAdd(&stats[tid], ls[tid]);
        atomicAdd(&stats[128 + tid], lq[tid]);
    }
}

// ---------------- phase P3a: per-block private LDS pooling partials ---------
__device__ void phase_p3a(int tid, int bid, const float* __restrict__ y3,
                          const float* __restrict__ st, const float* __restrict__ g,
                          const float* __restrict__ be, const float* __restrict__ pos,
                          unsigned* __restrict__ PK, float* __restrict__ PC,
                          float* __restrict__ PP, char* lds) {
    unsigned* lkey = (unsigned*)lds;             // 7200
    float* lcnt = (float*)(lds + 7200 * 4);      // 225
    float* lpac = (float*)(lds + 7425 * 4);      // 675
    for (int t = tid; t < 7200; t += 1024) lkey[t] = ENC_NEGINF;
    if (tid < 225) lcnt[tid] = 0.f;
    if (tid < 675) lpac[tid] = 0.f;
    __syncthreads();
    int s = bid >> 5, sb = bid & 31;
    int beg = s * 12500 + sb * 391;
    int end = min(s * 12500 + 12500, beg + 391);
    int c = tid & 31, nl = tid >> 5;
    float2 ss = bn_ss(st, g, be, c, INV_N);
    for (int i = beg + nl; i < end; i += 32) {
        float z = y3[(size_t)i * 32 + c] * ss.x + ss.y;
        float px = pos[i * 3], py = pos[i * 3 + 1];
        int cx = min(max((int)floorf(px / 16.f), 0), 14);
        int cy = min(max((int)floorf(py / 12.f), 0), 14);
        int cl = cy * 15 + cx;
        atomicMax(&lkey[cl * 32 + c], enc_f(z));
        if (c == 0) {
            atomicAdd(&lcnt[cl], 1.f);
            atomicAdd(&lpac[cl * 3 + 0], px);
            atomicAdd(&lpac[cl * 3 + 1], py);
            atomicAdd(&lpac[cl * 3 + 2], pos[i * 3 + 2]);
        }
    }
    __syncthreads();
    for (int t = tid; t < 7200; t += 1024) PK[(size_t)bid * 7200 + t] = lkey[t];
    if (tid < 225) PC[bid * 225 + tid] = lcnt[tid];
    if (tid < 675) PP[bid * 675 + tid] = lpac[tid];
}

// ---------------- phase P3b: merge 32 partials -> X2, POS2 ------------------
__device__ void phase_p3b(int gtid, const unsigned* __restrict__ PK,
                          const float* __restrict__ PC, const float* __restrict__ PP,
                          float* __restrict__ X2, float* __restrict__ POS2) {
    int idx = gtid;
    if (idx < 57600) {
        int s = idx / 7200, t = idx % 7200;
        unsigned m = ENC_NEGINF;
#pragma unroll 8
        for (int sb = 0; sb < 32; ++sb)
            m = max(m, PK[(size_t)(s * 32 + sb) * 7200 + t]);
        X2[idx] = (m == ENC_NEGINF) ? 0.f : dec_f(m);
    } else if (idx < 63000) {
        int j = idx - 57600;
        int s = j / 675, r = j % 675;
        int cl = r / 3;
        float sp = 0.f, sc = 0.f;
#pragma unroll 8
        for (int sb = 0; sb < 32; ++sb) {
            sp += PP[(s * 32 + sb) * 675 + r];
            sc += PC[(s * 32 + sb) * 225 + cl];
        }
        POS2[j] = sp / fmaxf(sc, 1.f);
    }
}

// ---------------- phase P5: blocks 0..7, LDS max, direct store --------------
__device__ void phase_p5(int tid, int bid, const float* __restrict__ y5,
                         const float* __restrict__ st, const float* __restrict__ g,
                         const float* __restrict__ be, const float* __restrict__ POS2,
                         float* __restrict__ POOLED, char* lds) {
    unsigned* lkey = (unsigned*)lds;   // 2048
    for (int t = tid; t < 2048; t += 1024) lkey[t] = ENC_NEGINF;
    __syncthreads();
    int s = bid;
    int c = tid & 127, nl = tid >> 7;
    float2 ss = bn_ss(st, g, be, c, INV_N2);
    for (int j = nl; j < 225; j += 8) {
        int i = s * 225 + j;
        float z = y5[(size_t)i * 128 + c] * ss.x + ss.y;
        float px = POS2[i * 3], py = POS2[i * 3 + 1];
        int cx = min(max((int)floorf(px / 60.f), 0), 3);
        int cy = min(max((int)floorf(py / 45.f), 0), 3);
        atomicMax(&lkey[(cy * 4 + cx) * 128 + c], enc_f(z));
    }
    __syncthreads();
    for (int t = tid; t < 2048; t += 1024) {
        unsigned k = lkey[t];
        POOLED[s * 2048 + t] = (k == ENC_NEGINF) ? 0.f : dec_f(k);
    }
}

// ---------------- phase FC: one wave per (b,o) ------------------------------
__device__ void phase_fc(int gtid, const float* __restrict__ POOLED,
                         const float* __restrict__ wfc, float* __restrict__ out) {
    int gw = gtid >> 6, lane = gtid & 63;
    if (gw < 808) {
        int b = gw / 101, o = gw % 101;
        float a = 0.f;
        for (int k = lane; k < 2048; k += 64)
            a += POOLED[b * 2048 + k] * wfc[k * 101 + o];
#pragma unroll
        for (int m = 32; m; m >>= 1) a += __shfl_xor(a, m);
        if (lane == 0) out[b * 101 + o] = a;
    }
}

// ---------------- the mega-kernel -------------------------------------------
__global__ __launch_bounds__(1024, 4) void mega(KArgs A) {
    __shared__ __align__(16) char smem[32400];
    cg::grid_group grid = cg::this_grid();
    int tid = threadIdx.x, bid = blockIdx.x;
    int gtid = bid * 1024 + tid;
    int gs = gridDim.x * 1024;
    float* ldsf = (float*)smem;

    // ph0: zero stats + L1 node transform
    for (int t = gtid; t < 1280; t += gs) A.STATS[t] = 0.f;
    phase_a<1, 8, 0>(gtid, gs, A.x, nullptr, nullptr, nullptr, 0.f, nullptr,
                     A.wl1, A.ws1, A.wp1, A.bp1, A.pos, A.SHPf, A.CAPf, nullptr, NN_FINE);
    grid.sync();
    phase_e<8, false>(tid, gtid, gs, A.SHPf, A.CAPf, A.e1, (float2*)A.Y1,
                      A.STATS + 0, ldsf, NN_FINE);
    grid.sync();
    phase_a<8, 8, 1>(gtid, gs, A.Y1, A.STATS + 0, A.g1, A.be1, INV_N, nullptr,
                     A.wl2, A.ws2, A.wp2, A.bp2, A.pos, A.SHPf, A.CAPf, A.Z1, NN_FINE);
    grid.sync();
    phase_e<8, false>(tid, gtid, gs, A.SHPf, A.CAPf, A.e1, (float2*)A.Y2,
                      A.STATS + 256, ldsf, NN_FINE);
    grid.sync();
    phase_a<8, 32, 2>(gtid, gs, A.Y2, A.STATS + 256, A.g2, A.be2, INV_N, A.Z1,
                      A.wl3, A.ws3, A.wp3, A.bp3, A.pos, A.SHPf, A.CAPf, nullptr, NN_FINE);
    grid.sync();
    phase_e<32, false>(tid, gtid, gs, A.SHPf, A.CAPf, A.e1, (float2*)A.Y3,
                       A.STATS + 512, ldsf, NN_FINE);
    grid.sync();
    phase_p3a(tid, bid, A.Y3, A.STATS + 512, A.g3, A.be3, A.pos, A.PK, A.PC, A.PP, smem);
    grid.sync();
    phase_p3b(gtid, A.PK, A.PC, A.PP, A.X2, A.POS2);
    grid.sync();
    phase_a<32, 32, 0>(gtid, gs, A.X2, nullptr, nullptr, nullptr, 0.f, nullptr,
                       A.wl4, A.ws4, A.wp4, A.bp4, A.POS2, A.SHPc, A.CAPc, nullptr, NN_COARSE);
    grid.sync();
    phase_e<32, true>(tid, gtid, gs, A.SHPc, A.CAPc, A.e2, (float2*)A.Y4,
                      A.STATS + 768, ldsf, NN_COARSE);
    grid.sync();
    phase_a<32, 128, 2>(gtid, gs, A.Y4, A.STATS + 768, A.g4, A.be4, INV_N2, A.X2,
                        A.wl5, A.ws5, A.wp5, A.bp5, A.POS2, A.SHPc, A.CAPc, nullptr, NN_COARSE);
    grid.sync();
    phase_e<128, true>(tid, gtid, gs, A.SHPc, A.CAPc, A.e2, (float2*)A.Y5,
                       A.STATS + 1024, ldsf, NN_COARSE);
    grid.sync();
    if (bid < 8)
        phase_p5(tid, bid, A.Y5, A.STATS + 1024, A.g5, A.be5, A.POS2, A.POOLED, smem);
    grid.sync();
    phase_fc(gtid, A.POOLED, A.wfc, A.out);
}

extern "C" void kernel_launch(void* const* d_in, const int* in_sizes, int n_in,
                              void* d_out, int out_size, void* d_ws, size_t ws_size,
                              hipStream_t stream) {
    auto F = [&](int idx) { return (const float*)d_in[idx]; };

    float* W = (float*)d_ws;
    size_t o = 0;
    KArgs A;
    A.x = F(0); A.pos = F(1);
    A.e1 = (const int*)d_in[3]; A.e2 = (const int*)d_in[4];
    A.wl1 = F(5);  A.ws1 = F(6);  A.wp1 = F(8);  A.bp1 = F(9);  A.g1 = F(10); A.be1 = F(11);
    A.wl2 = F(12); A.ws2 = F(13); A.wp2 = F(15); A.bp2 = F(16); A.g2 = F(17); A.be2 = F(18);
    A.wl3 = F(19); A.ws3 = F(20); A.wp3 = F(22); A.bp3 = F(23); A.g3 = F(24); A.be3 = F(25);
    A.wl4 = F(26); A.ws4 = F(27); A.wp4 = F(29); A.bp4 = F(30); A.g4 = F(31); A.be4 = F(32);
    A.wl5 = F(33); A.ws5 = F(34); A.wp5 = F(36); A.bp5 = F(37); A.g5 = F(38); A.be5 = F(39);
    A.wfc = F(40);

    A.SHPf = (float4*)W;          o += 6400000;   // N*16 floats (L1..L3)
    A.CAPf = (float2*)(W + o);    o += 3200000;
    A.Y1   = W + o;               o += 800000;
    A.Y2   = W + o;               o += 800000;
    A.Z1   = W + o;               o += 800000;
    A.Y3   = W + o;               o += 3200000;
    A.STATS = W + o;              o += 5 * 256;
    A.X2   = W + o;               o += 57600;
    A.POS2 = W + o;               o += 5400;
    A.SHPc = (float4*)(W + o);    o += 460800;
    A.CAPc = (float2*)(W + o);    o += 230400;
    A.Y4   = W + o;               o += 57600;
    A.Y5   = W + o;               o += 230400;
    A.POOLED = W + o;             o += 16384;
    // pool3 partials alias the (dead after E3) SHPf region:
    A.PK = (unsigned*)W;                          // 256*7200 u32
    A.PC = W + 2000000;                           // 256*225
    A.PP = W + 2100000;                           // 256*675
    A.out = (float*)d_out;

    void* kp[] = { (void*)&A };
    hipLaunchCooperativeKernel((void*)mega, dim3(256), dim3(1024), kp, 0, stream);
}

// Round 7
// 387.051 us; speedup vs baseline: 1.5240x; 1.5240x over previous
//
#include <hip/hip_runtime.h>

#define ENC_NEGINF 0x007FFFFFu
#define NN_FINE 100000
#define NN_COARSE 1800
#define INV_N  (1.0f / 100000.0f)
#define INV_N2 (1.0f / 1800.0f)

__device__ __forceinline__ unsigned enc_f(float f) {
    unsigned u = __float_as_uint(f);
    return (u & 0x80000000u) ? ~u : (u | 0x80000000u);
}
__device__ __forceinline__ float dec_f(unsigned k) {
    return (k & 0x80000000u) ? __uint_as_float(k & 0x7fffffffu) : __uint_as_float(~k);
}

// bijective XCD-aware swizzle (m204 variant)
__device__ __forceinline__ int xcd_swz(int bid, int nwg) {
    int q = nwg >> 3, r = nwg & 7;
    int xcd = bid & 7, idx = bid >> 3;
    return (xcd < r ? xcd * (q + 1) : r * (q + 1) + (xcd - r) * q) + idx;
}

__device__ __forceinline__ float2 bn_ss(const float* __restrict__ st,
                                        const float* __restrict__ g,
                                        const float* __restrict__ be,
                                        int r, float invn) {
    float mu  = st[r] * invn;
    float var = fmaxf(st[128 + r] * invn - mu * mu, 0.f);
    float s = g[r] * rsqrtf(var + 1e-5f);
    return make_float2(s, be[r] - mu * s);
}

// ---------------- PassA: per (node, channel-pair) ---------------------------
// MODE 0: f=in. 1: f=bn(in), write zout=bn(in). 2: f=bn(in)+skipf.
template<int CIN, int COUT, int MODE>
__global__ void pass_a(const float* __restrict__ in,
                       const float* __restrict__ st, const float* __restrict__ g,
                       const float* __restrict__ be, float invn,
                       const float* __restrict__ skipf,
                       const float* __restrict__ wl, const float* __restrict__ wsrc,
                       const float* __restrict__ wpos, const float* __restrict__ bpos,
                       const float* __restrict__ pos,
                       float4* __restrict__ SHP, float2* __restrict__ CAP,
                       float* __restrict__ zout, int NN) {
    constexpr int P = COUT / 2;
    int idx = blockIdx.x * blockDim.x + threadIdx.x;
    int i = idx / P, p = idx % P;
    if (i >= NN) return;
    float f[CIN];
#pragma unroll
    for (int r = 0; r < CIN; ++r) {
        float v = in[i * CIN + r];
        if constexpr (MODE >= 1) {
            float2 ss = bn_ss(st, g, be, r, invn);
            v = v * ss.x + ss.y;
        }
        if constexpr (MODE == 2) v += skipf[i * CIN + r];
        f[r] = v;
    }
    int c0 = 2 * p;
    float h0 = 0.f, a0 = 0.f, h1 = 0.f, a1 = 0.f;
#pragma unroll
    for (int r = 0; r < CIN; ++r) {
        float2 wlr = *reinterpret_cast<const float2*>(&wl[r * COUT + c0]);
        float2 wsr = *reinterpret_cast<const float2*>(&wsrc[r * COUT + c0]);
        h0 += f[r] * wlr.x; h1 += f[r] * wlr.y;
        a0 += f[r] * wsr.x; a1 += f[r] * wsr.y;
    }
    float px = pos[i * 3], py = pos[i * 3 + 1], pz = pos[i * 3 + 2];
    float2 w0 = *reinterpret_cast<const float2*>(&wpos[c0]);
    float2 w1 = *reinterpret_cast<const float2*>(&wpos[COUT + c0]);
    float2 w2 = *reinterpret_cast<const float2*>(&wpos[2 * COUT + c0]);
    float pd0 = px * w0.x + py * w1.x + pz * w2.x;
    float pd1 = px * w0.y + py * w1.y + pz * w2.y;
    float2 bp = *reinterpret_cast<const float2*>(&bpos[c0]);
    SHP[(size_t)i * P + p] = make_float4(a0 + pd0, a1 + pd1, h0 - pd0, h1 - pd1);
    CAP[(size_t)i * P + p] = make_float2(pd0 + bp.x, pd1 + bp.y);
    if constexpr (MODE == 1) {
        float2 s0 = bn_ss(st, g, be, c0, invn);
        float2 s1 = bn_ss(st, g, be, c0 + 1, invn);
        float2 zv = make_float2(in[i * CIN + c0] * s0.x + s0.y,
                                in[i * CIN + c0 + 1] * s1.x + s1.y);
        *reinterpret_cast<float2*>(&zout[i * CIN + c0]) = zv;
    }
}

// ---- Edge pass: 1 float4 gather per edge + fused BN-stats partials ---------
template<int C, bool COARSE>
__global__ __launch_bounds__(256, 4)
void edge_pass(const float4* __restrict__ SHP, const float2* __restrict__ CAP,
               const int* __restrict__ esrc, float2* __restrict__ y2,
               float* __restrict__ PS, int NN) {
    constexpr int P = C / 2;
    constexpr int NPB = 256 / P;
    constexpr int DEG_ = COARSE ? 8 : 16;
    __shared__ int se[NPB * DEG_];
    __shared__ float ls[C], lq[C];
    int bid = COARSE ? (int)blockIdx.x : xcd_swz(blockIdx.x, gridDim.x);
    int tid = threadIdx.x;
    int node0 = bid * NPB;
    if constexpr (!COARSE) {
        for (int t = tid; t < NPB * DEG_; t += 256)
            se[t] = esrc[node0 * 16 + t];          // in-bounds: dst half follows src
    } else {
        for (int t = tid; t < NPB * DEG_; t += 256) {
            int n = t / DEG_, e = t % DEG_;
            int i2 = node0 + n;
            if (i2 < NN) {
                int b = i2 / 225, j = i2 % 225;
                se[t] = esrc[b * 1800 + e * 225 + j];
            }
        }
    }
    if (tid < C) { ls[tid] = 0.f; lq[tid] = 0.f; }
    __syncthreads();
    int n = tid / P, p = tid % P;
    int i = node0 + n;
    float y0 = 0.f, y1 = 0.f;
    if (i < NN) {
        float4 q[DEG_ + 1];
#pragma unroll
        for (int e = 0; e < DEG_; ++e)
            q[e] = SHP[(size_t)se[n * DEG_ + e] * P + p];
        q[DEG_] = SHP[(size_t)i * P + p];

        float smin0 = q[0].x, smin1 = q[0].y;
#pragma unroll
        for (int e = 1; e <= DEG_; ++e) {
            smin0 = fminf(smin0, q[e].x);
            smin1 = fminf(smin1, q[e].y);
        }
        float den0 = 0.f, acc0 = 0.f, den1 = 0.f, acc1 = 0.f;
#pragma unroll
        for (int e = 0; e <= DEG_; ++e) {
            float ex0 = __expf(smin0 - q[e].x);
            float ex1 = __expf(smin1 - q[e].y);
            den0 += ex0; acc0 += ex0 * q[e].z;
            den1 += ex1; acc1 += ex1 * q[e].w;
        }
        float2 Ci = CAP[(size_t)i * P + p];
        float o0 = (acc0 + Ci.x * den0) / (den0 + 1e-16f);
        float o1 = (acc1 + Ci.y * den1) / (den1 + 1e-16f);
        y0 = o0 > 0.f ? o0 : (__expf(o0) - 1.f);
        y1 = o1 > 0.f ? o1 : (__expf(o1) - 1.f);
        y2[(size_t)i * P + p] = make_float2(y0, y1);
    }
    // BN-stats: wave reduce over same-p lanes, LDS merge, per-block partial
    float sa0 = y0, sq0 = y0 * y0, sa1 = y1, sq1 = y1 * y1;
    if constexpr (P < 64) {
#pragma unroll
        for (int m = P; m < 64; m <<= 1) {
            sa0 += __shfl_xor(sa0, m); sa1 += __shfl_xor(sa1, m);
            sq0 += __shfl_xor(sq0, m); sq1 += __shfl_xor(sq1, m);
        }
    }
    if ((tid & 63) < P) {
        int c0 = 2 * p;
        atomicAdd(&ls[c0], sa0); atomicAdd(&ls[c0 + 1], sa1);
        atomicAdd(&lq[c0], sq0); atomicAdd(&lq[c0 + 1], sq1);
    }
    __syncthreads();
    if (tid < C) {
        PS[(size_t)blockIdx.x * 2 * C + tid]     = ls[tid];
        PS[(size_t)blockIdx.x * 2 * C + C + tid] = lq[tid];
    }
}

// ---------------- stats reduce: nb per-block partials -> STATS --------------
template<int C>
__global__ __launch_bounds__(1024)
void stats_r(const float* __restrict__ PS, int nb, float* __restrict__ STATS) {
    constexpr int TC = 2 * C;            // TC divides 1024 (16/64/256)
    constexpr int NS = 1024 / TC;
    __shared__ float acc[1024];
    int tid = threadIdx.x;
    int c = tid % TC, sl = tid / TC;
    float s = 0.f;
    for (int b = sl; b < nb; b += NS)
        s += PS[(size_t)b * TC + c];
    acc[tid] = s;
    __syncthreads();
    if (tid < TC) {
        float t = 0.f;
#pragma unroll 8
        for (int s2 = 0; s2 < NS; ++s2) t += acc[s2 * TC + tid];
        if (tid < C) STATS[tid] = t;
        else         STATS[128 + (tid - C)] = t;
    }
}

// ---------------- pool3 stage 1: 32 blocks/sample, private LDS, partials ----
__global__ __launch_bounds__(256)
void pool3a(const float* __restrict__ y3, const float* __restrict__ st,
            const float* __restrict__ g, const float* __restrict__ be,
            const float* __restrict__ pos,
            unsigned* __restrict__ PK, float* __restrict__ PC,
            float* __restrict__ PP) {
    __shared__ unsigned lkey[7200];
    __shared__ float lcnt[225];
    __shared__ float lpac[675];
    int tid = threadIdx.x;
    for (int t = tid; t < 7200; t += 256) lkey[t] = ENC_NEGINF;
    if (tid < 225) lcnt[tid] = 0.f;
    for (int t = tid; t < 675; t += 256) lpac[t] = 0.f;
    __syncthreads();
    int bid = blockIdx.x;
    int s = bid >> 5, sb = bid & 31;
    int beg = s * 12500 + sb * 391;
    int end = min(s * 12500 + 12500, beg + 391);
    int c = tid & 31, nl = tid >> 5;
    float2 ss = bn_ss(st, g, be, c, INV_N);
    for (int i = beg + nl; i < end; i += 8) {
        float z = y3[(size_t)i * 32 + c] * ss.x + ss.y;
        float px = pos[i * 3], py = pos[i * 3 + 1];
        int cx = min(max((int)floorf(px / 16.f), 0), 14);
        int cy = min(max((int)floorf(py / 12.f), 0), 14);
        int cl = cy * 15 + cx;
        atomicMax(&lkey[cl * 32 + c], enc_f(z));
        if (c == 0) {
            atomicAdd(&lcnt[cl], 1.f);
            atomicAdd(&lpac[cl * 3 + 0], px);
            atomicAdd(&lpac[cl * 3 + 1], py);
            atomicAdd(&lpac[cl * 3 + 2], pos[i * 3 + 2]);
        }
    }
    __syncthreads();
    for (int t = tid; t < 7200; t += 256) PK[(size_t)bid * 7200 + t] = lkey[t];
    if (tid < 225) PC[bid * 225 + tid] = lcnt[tid];
    for (int t = tid; t < 675; t += 256) PP[bid * 675 + t] = lpac[t];
}

// ---------------- pool3 stage 2: reduce 32 partials -> X2, POS2 -------------
__global__ void pool3b(const unsigned* __restrict__ PK, const float* __restrict__ PC,
                       const float* __restrict__ PP,
                       float* __restrict__ X2, float* __restrict__ POS2) {
    int idx = blockIdx.x * blockDim.x + threadIdx.x;
    if (idx < 57600) {
        int s = idx / 7200, t = idx % 7200;
        unsigned m = ENC_NEGINF;
#pragma unroll 8
        for (int sb = 0; sb < 32; ++sb)
            m = max(m, PK[(size_t)(s * 32 + sb) * 7200 + t]);
        X2[idx] = (m == ENC_NEGINF) ? 0.f : dec_f(m);
    } else if (idx < 63000) {
        int j = idx - 57600;
        int s = j / 675, r = j % 675;
        int cl = r / 3;
        float sp = 0.f, sc = 0.f;
#pragma unroll 8
        for (int sb = 0; sb < 32; ++sb) {
            sp += PP[(s * 32 + sb) * 675 + r];
            sc += PC[(s * 32 + sb) * 225 + cl];
        }
        POS2[j] = sp / fmaxf(sc, 1.f);
    }
}

// ---------------- pool5 + FC fused: one block per sample --------------------
__global__ __launch_bounds__(1024)
void pool5fc(const float* __restrict__ y5, const float* __restrict__ st,
             const float* __restrict__ g, const float* __restrict__ be,
             const float* __restrict__ POS2, const float* __restrict__ wfc,
             float* __restrict__ out) {
    __shared__ unsigned lkey[2048];   // 16 cells x 128 ch
    __shared__ float row[2048];
    int tid = threadIdx.x, s = blockIdx.x;
    for (int t = tid; t < 2048; t += 1024) lkey[t] = ENC_NEGINF;
    __syncthreads();
    int c = tid & 127, nl = tid >> 7;
    float2 ss = bn_ss(st, g, be, c, INV_N2);
    for (int j = nl; j < 225; j += 8) {
        int i = s * 225 + j;
        float z = y5[(size_t)i * 128 + c] * ss.x + ss.y;
        float px = POS2[i * 3], py = POS2[i * 3 + 1];
        int cx = min(max((int)floorf(px / 60.f), 0), 3);
        int cy = min(max((int)floorf(py / 45.f), 0), 3);
        atomicMax(&lkey[(cy * 4 + cx) * 128 + c], enc_f(z));
    }
    __syncthreads();
    for (int t = tid; t < 2048; t += 1024) {
        unsigned k = lkey[t];
        row[t] = (k == ENC_NEGINF) ? 0.f : dec_f(k);
    }
    __syncthreads();
    int wv = tid >> 6, lane = tid & 63;
    for (int o = wv; o < 101; o += 16) {
        float a = 0.f;
        for (int k = lane; k < 2048; k += 64)
            a += row[k] * wfc[k * 101 + o];
#pragma unroll
        for (int m = 32; m; m >>= 1) a += __shfl_xor(a, m);
        if (lane == 0) out[s * 101 + o] = a;
    }
}

extern "C" void kernel_launch(void* const* d_in, const int* in_sizes, int n_in,
                              void* d_out, int out_size, void* d_ws, size_t ws_size,
                              hipStream_t stream) {
    const float* x     = (const float*)d_in[0];
    const float* pos   = (const float*)d_in[1];
    const int*   e1    = (const int*)d_in[3];
    const int*   e2    = (const int*)d_in[4];
    const float* w_fc  = (const float*)d_in[40];
    auto WL = [&](int l) { return (const float*)d_in[5 + l * 7 + 0]; };
    auto WS = [&](int l) { return (const float*)d_in[5 + l * 7 + 1]; };
    auto WP = [&](int l) { return (const float*)d_in[5 + l * 7 + 3]; };
    auto BP = [&](int l) { return (const float*)d_in[5 + l * 7 + 4]; };
    auto G_ = [&](int l) { return (const float*)d_in[5 + l * 7 + 5]; };
    auto BE = [&](int l) { return (const float*)d_in[5 + l * 7 + 6]; };

    float* W = (float*)d_ws;
    size_t o = 0;
    float4* SHPf = (float4*)W;        o += 6400000;  // N*16 floats (L1..L3)
    float2* CAPf = (float2*)(W + o);  o += 3200000;
    float*  Y1   = W + o;             o += 800000;
    float*  Y2   = W + o;             o += 800000;
    float*  Z1   = W + o;             o += 800000;
    float*  Y3   = W + o;             o += 3200000;
    float*  STATS = W + o;            o += 5 * 256;
    float*  X2   = W + o;             o += 57600;
    float*  POS2 = W + o;             o += 5400;
    float4* SHPc = (float4*)(W + o);  o += 460800;   // 1800*64 float4
    float2* CAPc = (float2*)(W + o);  o += 230400;
    float*  Y4   = W + o;             o += 57600;
    float*  Y5   = W + o;             o += 230400;
    float*  POOLED = W + o;           o += 16384;
    float*  PSTAT  = W + o;           o += 400000;   // max 6250 blocks * 64
    // pool3 partials alias the (dead after E3) SHPf region:
    unsigned* PK = (unsigned*)W;                  // 256*7200 u32
    float*    PC = W + 2000000;                   // 256*225
    float*    PP = W + 2100000;                   // 256*675

    // ---- L1 (1->8) fine ----
    hipLaunchKernelGGL((pass_a<1, 8, 0>), dim3(1563), dim3(256), 0, stream,
                       x, nullptr, nullptr, nullptr, 0.f, nullptr,
                       WL(0), WS(0), WP(0), BP(0), pos,
                       SHPf, CAPf, nullptr, NN_FINE);
    hipLaunchKernelGGL((edge_pass<8, false>), dim3(1563), dim3(256), 0, stream,
                       SHPf, CAPf, e1, (float2*)Y1, PSTAT, NN_FINE);
    hipLaunchKernelGGL((stats_r<8>), dim3(1), dim3(1024), 0, stream,
                       PSTAT, 1563, STATS + 0);

    // ---- L2 (8->8) fine, writes Z1=bn(Y1) ----
    hipLaunchKernelGGL((pass_a<8, 8, 1>), dim3(1563), dim3(256), 0, stream,
                       Y1, STATS + 0, G_(0), BE(0), INV_N, nullptr,
                       WL(1), WS(1), WP(1), BP(1), pos,
                       SHPf, CAPf, Z1, NN_FINE);
    hipLaunchKernelGGL((edge_pass<8, false>), dim3(1563), dim3(256), 0, stream,
                       SHPf, CAPf, e1, (float2*)Y2, PSTAT, NN_FINE);
    hipLaunchKernelGGL((stats_r<8>), dim3(1), dim3(1024), 0, stream,
                       PSTAT, 1563, STATS + 256);

    // ---- L3 (8->32) fine, f = bn(Y2)+Z1 ----
    hipLaunchKernelGGL((pass_a<8, 32, 2>), dim3(6250), dim3(256), 0, stream,
                       Y2, STATS + 256, G_(1), BE(1), INV_N, Z1,
                       WL(2), WS(2), WP(2), BP(2), pos,
                       SHPf, CAPf, nullptr, NN_FINE);
    hipLaunchKernelGGL((edge_pass<32, false>), dim3(6250), dim3(256), 0, stream,
                       SHPf, CAPf, e1, (float2*)Y3, PSTAT, NN_FINE);
    hipLaunchKernelGGL((stats_r<32>), dim3(1), dim3(1024), 0, stream,
                       PSTAT, 6250, STATS + 512);

    // ---- pool3: two-stage (SHPf region is dead now; partials alias it) ----
    hipLaunchKernelGGL(pool3a, dim3(256), dim3(256), 0, stream,
                       Y3, STATS + 512, G_(2), BE(2), pos, PK, PC, PP);
    hipLaunchKernelGGL(pool3b, dim3(247), dim3(256), 0, stream,
                       PK, PC, PP, X2, POS2);

    // ---- L4 (32->32) coarse ----
    hipLaunchKernelGGL((pass_a<32, 32, 0>), dim3(113), dim3(256), 0, stream,
                       X2, nullptr, nullptr, nullptr, 0.f, nullptr,
                       WL(3), WS(3), WP(3), BP(3), POS2,
                       SHPc, CAPc, nullptr, NN_COARSE);
    hipLaunchKernelGGL((edge_pass<32, true>), dim3(113), dim3(256), 0, stream,
                       SHPc, CAPc, e2, (float2*)Y4, PSTAT, NN_COARSE);
    hipLaunchKernelGGL((stats_r<32>), dim3(1), dim3(1024), 0, stream,
                       PSTAT, 113, STATS + 768);

    // ---- L5 (32->128) coarse, f = bn(Y4)+X2 ----
    hipLaunchKernelGGL((pass_a<32, 128, 2>), dim3(450), dim3(256), 0, stream,
                       Y4, STATS + 768, G_(3), BE(3), INV_N2, X2,
                       WL(4), WS(4), WP(4), BP(4), POS2,
                       SHPc, CAPc, nullptr, NN_COARSE);
    hipLaunchKernelGGL((edge_pass<128, true>), dim3(450), dim3(256), 0, stream,
                       SHPc, CAPc, e2, (float2*)Y5, PSTAT, NN_COARSE);
    hipLaunchKernelGGL((stats_r<128>), dim3(1), dim3(1024), 0, stream,
                       PSTAT, 450, STATS + 1024);

    // ---- pool5 + FC fused ----
    hipLaunchKernelGGL(pool5fc, dim3(8), dim3(1024), 0, stream,
                       Y5, STATS + 1024, G_(4), BE(4), POS2, w_fc, (float*)d_out);
}

// Round 8
// 271.152 us; speedup vs baseline: 2.1753x; 1.4274x over previous
//
#include <hip/hip_runtime.h>

#define ENC_NEGINF 0x007FFFFFu
#define NN_FINE 100000
#define NN_COARSE 1800
#define INV_N  (1.0f / 100000.0f)
#define INV_N2 (1.0f / 1800.0f)

__device__ __forceinline__ unsigned enc_f(float f) {
    unsigned u = __float_as_uint(f);
    return (u & 0x80000000u) ? ~u : (u | 0x80000000u);
}
__device__ __forceinline__ float dec_f(unsigned k) {
    return (k & 0x80000000u) ? __uint_as_float(k & 0x7fffffffu) : __uint_as_float(~k);
}

// bijective XCD-aware swizzle (m204 variant)
__device__ __forceinline__ int xcd_swz(int bid, int nwg) {
    int q = nwg >> 3, r = nwg & 7;
    int xcd = bid & 7, idx = bid >> 3;
    return (xcd < r ? xcd * (q + 1) : r * (q + 1) + (xcd - r) * q) + idx;
}

__device__ __forceinline__ float2 bn_ss(const float* __restrict__ st,
                                        const float* __restrict__ g,
                                        const float* __restrict__ be,
                                        int r, float invn) {
    float mu  = st[r] * invn;
    float var = fmaxf(st[128 + r] * invn - mu * mu, 0.f);
    float s = g[r] * rsqrtf(var + 1e-5f);
    return make_float2(s, be[r] - mu * s);
}

// ---------------- init: zero BN stats (atomic targets) ----------------------
__global__ void init_k(float* stats) {
    int t = blockIdx.x * blockDim.x + threadIdx.x;
    if (t < 1280) stats[t] = 0.f;
}

// ---------------- PassA: per (node, channel-pair) ---------------------------
// MODE 0: f=in. 1: f=bn(in), write zout=bn(in). 2: f=bn(in)+skipf.
template<int CIN, int COUT, int MODE>
__global__ void pass_a(const float* __restrict__ in,
                       const float* __restrict__ st, const float* __restrict__ g,
                       const float* __restrict__ be, float invn,
                       const float* __restrict__ skipf,
                       const float* __restrict__ wl, const float* __restrict__ wsrc,
                       const float* __restrict__ wpos, const float* __restrict__ bpos,
                       const float* __restrict__ pos,
                       float4* __restrict__ SHP, float2* __restrict__ CAP,
                       float* __restrict__ zout, int NN) {
    constexpr int P = COUT / 2;
    int idx = blockIdx.x * blockDim.x + threadIdx.x;
    int i = idx / P, p = idx % P;
    if (i >= NN) return;
    float f[CIN];
#pragma unroll
    for (int r = 0; r < CIN; ++r) {
        float v = in[i * CIN + r];
        if constexpr (MODE >= 1) {
            float2 ss = bn_ss(st, g, be, r, invn);
            v = v * ss.x + ss.y;
        }
        if constexpr (MODE == 2) v += skipf[i * CIN + r];
        f[r] = v;
    }
    int c0 = 2 * p;
    float h0 = 0.f, a0 = 0.f, h1 = 0.f, a1 = 0.f;
#pragma unroll
    for (int r = 0; r < CIN; ++r) {
        float2 wlr = *reinterpret_cast<const float2*>(&wl[r * COUT + c0]);
        float2 wsr = *reinterpret_cast<const float2*>(&wsrc[r * COUT + c0]);
        h0 += f[r] * wlr.x; h1 += f[r] * wlr.y;
        a0 += f[r] * wsr.x; a1 += f[r] * wsr.y;
    }
    float px = pos[i * 3], py = pos[i * 3 + 1], pz = pos[i * 3 + 2];
    float2 w0 = *reinterpret_cast<const float2*>(&wpos[c0]);
    float2 w1 = *reinterpret_cast<const float2*>(&wpos[COUT + c0]);
    float2 w2 = *reinterpret_cast<const float2*>(&wpos[2 * COUT + c0]);
    float pd0 = px * w0.x + py * w1.x + pz * w2.x;
    float pd1 = px * w0.y + py * w1.y + pz * w2.y;
    float2 bp = *reinterpret_cast<const float2*>(&bpos[c0]);
    SHP[(size_t)i * P + p] = make_float4(a0 + pd0, a1 + pd1, h0 - pd0, h1 - pd1);
    CAP[(size_t)i * P + p] = make_float2(pd0 + bp.x, pd1 + bp.y);
    if constexpr (MODE == 1) {
        float2 s0 = bn_ss(st, g, be, c0, invn);
        float2 s1 = bn_ss(st, g, be, c0 + 1, invn);
        float2 zv = make_float2(in[i * CIN + c0] * s0.x + s0.y,
                                in[i * CIN + c0 + 1] * s1.x + s1.y);
        *reinterpret_cast<float2*>(&zout[i * CIN + c0]) = zv;
    }
}

// ---- Edge pass: 1 float4 gather per edge + fused BN-stats partials ---------
template<int C, bool COARSE>
__global__ __launch_bounds__(256, 4)
void edge_pass(const float4* __restrict__ SHP, const float2* __restrict__ CAP,
               const int* __restrict__ esrc, float2* __restrict__ y2,
               float* __restrict__ PS, int NN) {
    constexpr int P = C / 2;
    constexpr int NPB = 256 / P;
    constexpr int DEG_ = COARSE ? 8 : 16;
    __shared__ int se[NPB * DEG_];
    __shared__ float ls[C], lq[C];
    int bid = COARSE ? (int)blockIdx.x : xcd_swz(blockIdx.x, gridDim.x);
    int tid = threadIdx.x;
    int node0 = bid * NPB;
    if constexpr (!COARSE) {
        for (int t = tid; t < NPB * DEG_; t += 256)
            se[t] = esrc[node0 * 16 + t];          // in-bounds: dst half follows src
    } else {
        for (int t = tid; t < NPB * DEG_; t += 256) {
            int n = t / DEG_, e = t % DEG_;
            int i2 = node0 + n;
            if (i2 < NN) {
                int b = i2 / 225, j = i2 % 225;
                se[t] = esrc[b * 1800 + e * 225 + j];
            }
        }
    }
    if (tid < C) { ls[tid] = 0.f; lq[tid] = 0.f; }
    __syncthreads();
    int n = tid / P, p = tid % P;
    int i = node0 + n;
    float y0 = 0.f, y1 = 0.f;
    if (i < NN) {
        float4 q[DEG_ + 1];
#pragma unroll
        for (int e = 0; e < DEG_; ++e)
            q[e] = SHP[(size_t)se[n * DEG_ + e] * P + p];
        q[DEG_] = SHP[(size_t)i * P + p];

        float smin0 = q[0].x, smin1 = q[0].y;
#pragma unroll
        for (int e = 1; e <= DEG_; ++e) {
            smin0 = fminf(smin0, q[e].x);
            smin1 = fminf(smin1, q[e].y);
        }
        float den0 = 0.f, acc0 = 0.f, den1 = 0.f, acc1 = 0.f;
#pragma unroll
        for (int e = 0; e <= DEG_; ++e) {
            float ex0 = __expf(smin0 - q[e].x);
            float ex1 = __expf(smin1 - q[e].y);
            den0 += ex0; acc0 += ex0 * q[e].z;
            den1 += ex1; acc1 += ex1 * q[e].w;
        }
        float2 Ci = CAP[(size_t)i * P + p];
        float o0 = (acc0 + Ci.x * den0) / (den0 + 1e-16f);
        float o1 = (acc1 + Ci.y * den1) / (den1 + 1e-16f);
        y0 = o0 > 0.f ? o0 : (__expf(o0) - 1.f);
        y1 = o1 > 0.f ? o1 : (__expf(o1) - 1.f);
        y2[(size_t)i * P + p] = make_float2(y0, y1);
    }
    // BN-stats: wave reduce over same-p lanes, LDS merge, per-block partial
    float sa0 = y0, sq0 = y0 * y0, sa1 = y1, sq1 = y1 * y1;
    if constexpr (P < 64) {
#pragma unroll
        for (int m = P; m < 64; m <<= 1) {
            sa0 += __shfl_xor(sa0, m); sa1 += __shfl_xor(sa1, m);
            sq0 += __shfl_xor(sq0, m); sq1 += __shfl_xor(sq1, m);
        }
    }
    if ((tid & 63) < P) {
        int c0 = 2 * p;
        atomicAdd(&ls[c0], sa0); atomicAdd(&ls[c0 + 1], sa1);
        atomicAdd(&lq[c0], sq0); atomicAdd(&lq[c0 + 1], sq1);
    }
    __syncthreads();
    if (tid < C) {
        PS[(size_t)blockIdx.x * 2 * C + tid]     = ls[tid];
        PS[(size_t)blockIdx.x * 2 * C + C + tid] = lq[tid];
    }
}

// ------- stats reduce: nb per-block partials -> STATS (multi-block) ---------
template<int C>
__global__ __launch_bounds__(256)
void stats_r(const float* __restrict__ PS, int nb, float* __restrict__ STATS) {
    constexpr int TC = 2 * C;            // 16 / 64 / 256 — divides 256
    constexpr int NS = 256 / TC;
    __shared__ float acc[256];
    int tid = threadIdx.x;
    int c = tid % TC, sl = tid / TC;
    float s = 0.f;
    for (int b = blockIdx.x * NS + sl; b < nb; b += gridDim.x * NS)
        s += PS[(size_t)b * TC + c];
    acc[tid] = s;
    __syncthreads();
    if (tid < TC) {
        float t = s;
        if (tid >= NS * TC - TC) t = 0.f;   // (guard unused; NS*TC==256 always)
        t = 0.f;
#pragma unroll
        for (int s2 = 0; s2 < NS; ++s2) t += acc[s2 * TC + tid];
        float* dst = (tid < C) ? &STATS[tid] : &STATS[128 + (tid - C)];
        atomicAdd(dst, t);
    }
}

// ---------------- pool3 stage 1: 32 blocks/sample, private LDS, partials ----
__global__ __launch_bounds__(256)
void pool3a(const float* __restrict__ y3, const float* __restrict__ st,
            const float* __restrict__ g, const float* __restrict__ be,
            const float* __restrict__ pos,
            unsigned* __restrict__ PK, float* __restrict__ PC,
            float* __restrict__ PP) {
    __shared__ unsigned lkey[7200];
    __shared__ float lcnt[225];
    __shared__ float lpac[675];
    int tid = threadIdx.x;
    for (int t = tid; t < 7200; t += 256) lkey[t] = ENC_NEGINF;
    if (tid < 225) lcnt[tid] = 0.f;
    for (int t = tid; t < 675; t += 256) lpac[t] = 0.f;
    __syncthreads();
    int bid = blockIdx.x;
    int s = bid >> 5, sb = bid & 31;
    int beg = s * 12500 + sb * 391;
    int end = min(s * 12500 + 12500, beg + 391);
    int c = tid & 31, nl = tid >> 5;
    float2 ss = bn_ss(st, g, be, c, INV_N);
    for (int i = beg + nl; i < end; i += 8) {
        float z = y3[(size_t)i * 32 + c] * ss.x + ss.y;
        float px = pos[i * 3], py = pos[i * 3 + 1];
        int cx = min(max((int)floorf(px / 16.f), 0), 14);
        int cy = min(max((int)floorf(py / 12.f), 0), 14);
        int cl = cy * 15 + cx;
        atomicMax(&lkey[cl * 32 + c], enc_f(z));
        if (c == 0) {
            atomicAdd(&lcnt[cl], 1.f);
            atomicAdd(&lpac[cl * 3 + 0], px);
            atomicAdd(&lpac[cl * 3 + 1], py);
            atomicAdd(&lpac[cl * 3 + 2], pos[i * 3 + 2]);
        }
    }
    __syncthreads();
    for (int t = tid; t < 7200; t += 256) PK[(size_t)bid * 7200 + t] = lkey[t];
    if (tid < 225) PC[bid * 225 + tid] = lcnt[tid];
    for (int t = tid; t < 675; t += 256) PP[bid * 675 + t] = lpac[t];
}

// ---------------- pool3 stage 2: reduce 32 partials -> X2, POS2 -------------
__global__ void pool3b(const unsigned* __restrict__ PK, const float* __restrict__ PC,
                       const float* __restrict__ PP,
                       float* __restrict__ X2, float* __restrict__ POS2) {
    int idx = blockIdx.x * blockDim.x + threadIdx.x;
    if (idx < 57600) {
        int s = idx / 7200, t = idx % 7200;
        unsigned m = ENC_NEGINF;
#pragma unroll 8
        for (int sb = 0; sb < 32; ++sb)
            m = max(m, PK[(size_t)(s * 32 + sb) * 7200 + t]);
        X2[idx] = (m == ENC_NEGINF) ? 0.f : dec_f(m);
    } else if (idx < 63000) {
        int j = idx - 57600;
        int s = j / 675, r = j % 675;
        int cl = r / 3;
        float sp = 0.f, sc = 0.f;
#pragma unroll 8
        for (int sb = 0; sb < 32; ++sb) {
            sp += PP[(s * 32 + sb) * 675 + r];
            sc += PC[(s * 32 + sb) * 225 + cl];
        }
        POS2[j] = sp / fmaxf(sc, 1.f);
    }
}

// ---------------- pool5 + FC fused: one block per sample --------------------
__global__ __launch_bounds__(1024)
void pool5fc(const float* __restrict__ y5, const float* __restrict__ st,
             const float* __restrict__ g, const float* __restrict__ be,
             const float* __restrict__ POS2, const float* __restrict__ wfc,
             float* __restrict__ out) {
    __shared__ unsigned lkey[2048];   // 16 cells x 128 ch
    __shared__ float row[2048];
    int tid = threadIdx.x, s = blockIdx.x;
    for (int t = tid; t < 2048; t += 1024) lkey[t] = ENC_NEGINF;
    __syncthreads();
    int c = tid & 127, nl = tid >> 7;
    float2 ss = bn_ss(st, g, be, c, INV_N2);
    for (int j = nl; j < 225; j += 8) {
        int i = s * 225 + j;
        float z = y5[(size_t)i * 128 + c] * ss.x + ss.y;
        float px = POS2[i * 3], py = POS2[i * 3 + 1];
        int cx = min(max((int)floorf(px / 60.f), 0), 3);
        int cy = min(max((int)floorf(py / 45.f), 0), 3);
        atomicMax(&lkey[(cy * 4 + cx) * 128 + c], enc_f(z));
    }
    __syncthreads();
    for (int t = tid; t < 2048; t += 1024) {
        unsigned k = lkey[t];
        row[t] = (k == ENC_NEGINF) ? 0.f : dec_f(k);
    }
    __syncthreads();
    int wv = tid >> 6, lane = tid & 63;
    for (int o = wv; o < 101; o += 16) {
        float a = 0.f;
        for (int k = lane; k < 2048; k += 64)
            a += row[k] * wfc[k * 101 + o];
#pragma unroll
        for (int m = 32; m; m >>= 1) a += __shfl_xor(a, m);
        if (lane == 0) out[s * 101 + o] = a;
    }
}

extern "C" void kernel_launch(void* const* d_in, const int* in_sizes, int n_in,
                              void* d_out, int out_size, void* d_ws, size_t ws_size,
                              hipStream_t stream) {
    const float* x     = (const float*)d_in[0];
    const float* pos   = (const float*)d_in[1];
    const int*   e1    = (const int*)d_in[3];
    const int*   e2    = (const int*)d_in[4];
    const float* w_fc  = (const float*)d_in[40];
    auto WL = [&](int l) { return (const float*)d_in[5 + l * 7 + 0]; };
    auto WS = [&](int l) { return (const float*)d_in[5 + l * 7 + 1]; };
    auto WP = [&](int l) { return (const float*)d_in[5 + l * 7 + 3]; };
    auto BP = [&](int l) { return (const float*)d_in[5 + l * 7 + 4]; };
    auto G_ = [&](int l) { return (const float*)d_in[5 + l * 7 + 5]; };
    auto BE = [&](int l) { return (const float*)d_in[5 + l * 7 + 6]; };

    float* W = (float*)d_ws;
    size_t o = 0;
    float4* SHPf = (float4*)W;        o += 6400000;  // N*16 floats (L1..L3)
    float2* CAPf = (float2*)(W + o);  o += 3200000;
    float*  Y1   = W + o;             o += 800000;
    float*  Y2   = W + o;             o += 800000;
    float*  Z1   = W + o;             o += 800000;
    float*  Y3   = W + o;             o += 3200000;
    float*  STATS = W + o;            o += 5 * 256;
    float*  X2   = W + o;             o += 57600;
    float*  POS2 = W + o;             o += 5400;
    float4* SHPc = (float4*)(W + o);  o += 460800;   // 1800*64 float4
    float2* CAPc = (float2*)(W + o);  o += 230400;
    float*  Y4   = W + o;             o += 57600;
    float*  Y5   = W + o;             o += 230400;
    float*  POOLED = W + o;           o += 16384;
    float*  PSTAT  = W + o;           o += 400000;   // max 6250 blocks * 64
    // pool3 partials alias the (dead after E3) SHPf region:
    unsigned* PK = (unsigned*)W;                  // 256*7200 u32
    float*    PC = W + 2000000;                   // 256*225
    float*    PP = W + 2100000;                   // 256*675

    hipLaunchKernelGGL(init_k, dim3(2), dim3(1024), 0, stream, STATS);

    // ---- L1 (1->8) fine ----
    hipLaunchKernelGGL((pass_a<1, 8, 0>), dim3(1563), dim3(256), 0, stream,
                       x, nullptr, nullptr, nullptr, 0.f, nullptr,
                       WL(0), WS(0), WP(0), BP(0), pos,
                       SHPf, CAPf, nullptr, NN_FINE);
    hipLaunchKernelGGL((edge_pass<8, false>), dim3(1563), dim3(256), 0, stream,
                       SHPf, CAPf, e1, (float2*)Y1, PSTAT, NN_FINE);
    hipLaunchKernelGGL((stats_r<8>), dim3(32), dim3(256), 0, stream,
                       PSTAT, 1563, STATS + 0);

    // ---- L2 (8->8) fine, writes Z1=bn(Y1) ----
    hipLaunchKernelGGL((pass_a<8, 8, 1>), dim3(1563), dim3(256), 0, stream,
                       Y1, STATS + 0, G_(0), BE(0), INV_N, nullptr,
                       WL(1), WS(1), WP(1), BP(1), pos,
                       SHPf, CAPf, Z1, NN_FINE);
    hipLaunchKernelGGL((edge_pass<8, false>), dim3(1563), dim3(256), 0, stream,
                       SHPf, CAPf, e1, (float2*)Y2, PSTAT, NN_FINE);
    hipLaunchKernelGGL((stats_r<8>), dim3(32), dim3(256), 0, stream,
                       PSTAT, 1563, STATS + 256);

    // ---- L3 (8->32) fine, f = bn(Y2)+Z1 ----
    hipLaunchKernelGGL((pass_a<8, 32, 2>), dim3(6250), dim3(256), 0, stream,
                       Y2, STATS + 256, G_(1), BE(1), INV_N, Z1,
                       WL(2), WS(2), WP(2), BP(2), pos,
                       SHPf, CAPf, nullptr, NN_FINE);
    hipLaunchKernelGGL((edge_pass<32, false>), dim3(6250), dim3(256), 0, stream,
                       SHPf, CAPf, e1, (float2*)Y3, PSTAT, NN_FINE);
    hipLaunchKernelGGL((stats_r<32>), dim3(32), dim3(256), 0, stream,
                       PSTAT, 6250, STATS + 512);

    // ---- pool3: two-stage (SHPf region is dead now; partials alias it) ----
    hipLaunchKernelGGL(pool3a, dim3(256), dim3(256), 0, stream,
                       Y3, STATS + 512, G_(2), BE(2), pos, PK, PC, PP);
    hipLaunchKernelGGL(pool3b, dim3(247), dim3(256), 0, stream,
                       PK, PC, PP, X2, POS2);

    // ---- L4 (32->32) coarse ----
    hipLaunchKernelGGL((pass_a<32, 32, 0>), dim3(113), dim3(256), 0, stream,
                       X2, nullptr, nullptr, nullptr, 0.f, nullptr,
                       WL(3), WS(3), WP(3), BP(3), POS2,
                       SHPc, CAPc, nullptr, NN_COARSE);
    hipLaunchKernelGGL((edge_pass<32, true>), dim3(113), dim3(256), 0, stream,
                       SHPc, CAPc, e2, (float2*)Y4, PSTAT, NN_COARSE);
    hipLaunchKernelGGL((stats_r<32>), dim3(16), dim3(256), 0, stream,
                       PSTAT, 113, STATS + 768);

    // ---- L5 (32->128) coarse, f = bn(Y4)+X2 ----
    hipLaunchKernelGGL((pass_a<32, 128, 2>), dim3(450), dim3(256), 0, stream,
                       Y4, STATS + 768, G_(3), BE(3), INV_N2, X2,
                       WL(4), WS(4), WP(4), BP(4), POS2,
                       SHPc, CAPc, nullptr, NN_COARSE);
    hipLaunchKernelGGL((edge_pass<128, true>), dim3(450), dim3(256), 0, stream,
                       SHPc, CAPc, e2, (float2*)Y5, PSTAT, NN_COARSE);
    hipLaunchKernelGGL((stats_r<128>), dim3(16), dim3(256), 0, stream,
                       PSTAT, 450, STATS + 1024);

    // ---- pool5 + FC fused ----
    hipLaunchKernelGGL(pool5fc, dim3(8), dim3(1024), 0, stream,
                       Y5, STATS + 1024, G_(4), BE(4), POS2, w_fc, (float*)d_out);
}

// Round 9
// 228.131 us; speedup vs baseline: 2.5856x; 1.1886x over previous
//
#include <hip/hip_runtime.h>

#define ENC_NEGINF 0x007FFFFFu
#define NN_FINE 100000
#define NN_COARSE 1800
#define INV_N  (1.0f / 100000.0f)
#define INV_N2 (1.0f / 1800.0f)

__device__ __forceinline__ unsigned enc_f(float f) {
    unsigned u = __float_as_uint(f);
    return (u & 0x80000000u) ? ~u : (u | 0x80000000u);
}
__device__ __forceinline__ float dec_f(unsigned k) {
    return (k & 0x80000000u) ? __uint_as_float(k & 0x7fffffffu) : __uint_as_float(~k);
}

// bijective XCD-aware swizzle (m204 variant)
__device__ __forceinline__ int xcd_swz(int bid, int nwg) {
    int q = nwg >> 3, r = nwg & 7;
    int xcd = bid & 7, idx = bid >> 3;
    return (xcd < r ? xcd * (q + 1) : r * (q + 1) + (xcd - r) * q) + idx;
}

__device__ __forceinline__ float2 bn_ss(const float* __restrict__ st,
                                        const float* __restrict__ g,
                                        const float* __restrict__ be,
                                        int r, float invn) {
    float mu  = st[r] * invn;
    float var = fmaxf(st[128 + r] * invn - mu * mu, 0.f);
    float s = g[r] * rsqrtf(var + 1e-5f);
    return make_float2(s, be[r] - mu * s);
}

// ---------------- init: zero BN stats + output (atomic targets) -------------
__global__ void init_k(float* stats, float* out) {
    int t = blockIdx.x * blockDim.x + threadIdx.x;
    if (t < 1280) stats[t] = 0.f;
    if (t < 808)  out[t] = 0.f;
}

// ---------------- PassA: per (node, channel-pair) ---------------------------
// MODE 0: f=in. 1: f=bn(in), write zout=bn(in). 2: f=bn(in)+skipf.
template<int CIN, int COUT, int MODE>
__global__ void pass_a(const float* __restrict__ in,
                       const float* __restrict__ st, const float* __restrict__ g,
                       const float* __restrict__ be, float invn,
                       const float* __restrict__ skipf,
                       const float* __restrict__ wl, const float* __restrict__ wsrc,
                       const float* __restrict__ wpos, const float* __restrict__ bpos,
                       const float* __restrict__ pos,
                       float4* __restrict__ SHP, float2* __restrict__ CAP,
                       float* __restrict__ zout, int NN) {
    constexpr int P = COUT / 2;
    int idx = blockIdx.x * blockDim.x + threadIdx.x;
    int i = idx / P, p = idx % P;
    if (i >= NN) return;
    float f[CIN];
#pragma unroll
    for (int r = 0; r < CIN; ++r) {
        float v = in[i * CIN + r];
        if constexpr (MODE >= 1) {
            float2 ss = bn_ss(st, g, be, r, invn);
            v = v * ss.x + ss.y;
        }
        if constexpr (MODE == 2) v += skipf[i * CIN + r];
        f[r] = v;
    }
    int c0 = 2 * p;
    float h0 = 0.f, a0 = 0.f, h1 = 0.f, a1 = 0.f;
#pragma unroll
    for (int r = 0; r < CIN; ++r) {
        float2 wlr = *reinterpret_cast<const float2*>(&wl[r * COUT + c0]);
        float2 wsr = *reinterpret_cast<const float2*>(&wsrc[r * COUT + c0]);
        h0 += f[r] * wlr.x; h1 += f[r] * wlr.y;
        a0 += f[r] * wsr.x; a1 += f[r] * wsr.y;
    }
    float px = pos[i * 3], py = pos[i * 3 + 1], pz = pos[i * 3 + 2];
    float2 w0 = *reinterpret_cast<const float2*>(&wpos[c0]);
    float2 w1 = *reinterpret_cast<const float2*>(&wpos[COUT + c0]);
    float2 w2 = *reinterpret_cast<const float2*>(&wpos[2 * COUT + c0]);
    float pd0 = px * w0.x + py * w1.x + pz * w2.x;
    float pd1 = px * w0.y + py * w1.y + pz * w2.y;
    float2 bp = *reinterpret_cast<const float2*>(&bpos[c0]);
    SHP[(size_t)i * P + p] = make_float4(a0 + pd0, a1 + pd1, h0 - pd0, h1 - pd1);
    CAP[(size_t)i * P + p] = make_float2(pd0 + bp.x, pd1 + bp.y);
    if constexpr (MODE == 1) {
        float2 s0 = bn_ss(st, g, be, c0, invn);
        float2 s1 = bn_ss(st, g, be, c0 + 1, invn);
        float2 zv = make_float2(in[i * CIN + c0] * s0.x + s0.y,
                                in[i * CIN + c0 + 1] * s1.x + s1.y);
        *reinterpret_cast<float2*>(&zout[i * CIN + c0]) = zv;
    }
}

// ---- Edge pass: 1 float4 gather per edge + fused BN-stats partials ---------
template<int C, bool COARSE>
__global__ __launch_bounds__(256, 4)
void edge_pass(const float4* __restrict__ SHP, const float2* __restrict__ CAP,
               const int* __restrict__ esrc, float2* __restrict__ y2,
               float* __restrict__ PS, int NN) {
    constexpr int P = C / 2;
    constexpr int NPB = 256 / P;
    constexpr int DEG_ = COARSE ? 8 : 16;
    __shared__ int se[NPB * DEG_];
    __shared__ float ls[C], lq[C];
    int bid = COARSE ? (int)blockIdx.x : xcd_swz(blockIdx.x, gridDim.x);
    int tid = threadIdx.x;
    int node0 = bid * NPB;
    if constexpr (!COARSE) {
        for (int t = tid; t < NPB * DEG_; t += 256)
            se[t] = esrc[node0 * 16 + t];          // in-bounds: dst half follows src
    } else {
        for (int t = tid; t < NPB * DEG_; t += 256) {
            int n = t / DEG_, e = t % DEG_;
            int i2 = node0 + n;
            if (i2 < NN) {
                int b = i2 / 225, j = i2 % 225;
                se[t] = esrc[b * 1800 + e * 225 + j];
            }
        }
    }
    if (tid < C) { ls[tid] = 0.f; lq[tid] = 0.f; }
    __syncthreads();
    int n = tid / P, p = tid % P;
    int i = node0 + n;
    float y0 = 0.f, y1 = 0.f;
    if (i < NN) {
        float4 q[DEG_ + 1];
#pragma unroll
        for (int e = 0; e < DEG_; ++e)
            q[e] = SHP[(size_t)se[n * DEG_ + e] * P + p];
        q[DEG_] = SHP[(size_t)i * P + p];

        float smin0 = q[0].x, smin1 = q[0].y;
#pragma unroll
        for (int e = 1; e <= DEG_; ++e) {
            smin0 = fminf(smin0, q[e].x);
            smin1 = fminf(smin1, q[e].y);
        }
        float den0 = 0.f, acc0 = 0.f, den1 = 0.f, acc1 = 0.f;
#pragma unroll
        for (int e = 0; e <= DEG_; ++e) {
            float ex0 = __expf(smin0 - q[e].x);
            float ex1 = __expf(smin1 - q[e].y);
            den0 += ex0; acc0 += ex0 * q[e].z;
            den1 += ex1; acc1 += ex1 * q[e].w;
        }
        float2 Ci = CAP[(size_t)i * P + p];
        float o0 = (acc0 + Ci.x * den0) / (den0 + 1e-16f);
        float o1 = (acc1 + Ci.y * den1) / (den1 + 1e-16f);
        y0 = o0 > 0.f ? o0 : (__expf(o0) - 1.f);
        y1 = o1 > 0.f ? o1 : (__expf(o1) - 1.f);
        y2[(size_t)i * P + p] = make_float2(y0, y1);
    }
    // BN-stats: wave reduce over same-p lanes, LDS merge, per-block partial
    float sa0 = y0, sq0 = y0 * y0, sa1 = y1, sq1 = y1 * y1;
    if constexpr (P < 64) {
#pragma unroll
        for (int m = P; m < 64; m <<= 1) {
            sa0 += __shfl_xor(sa0, m); sa1 += __shfl_xor(sa1, m);
            sq0 += __shfl_xor(sq0, m); sq1 += __shfl_xor(sq1, m);
        }
    }
    if ((tid & 63) < P) {
        int c0 = 2 * p;
        atomicAdd(&ls[c0], sa0); atomicAdd(&ls[c0 + 1], sa1);
        atomicAdd(&lq[c0], sq0); atomicAdd(&lq[c0 + 1], sq1);
    }
    __syncthreads();
    if (tid < C) {
        PS[(size_t)blockIdx.x * 2 * C + tid]     = ls[tid];
        PS[(size_t)blockIdx.x * 2 * C + C + tid] = lq[tid];
    }
}

// ------- stats reduce: nb per-block partials -> STATS (multi-block) ---------
template<int C>
__global__ __launch_bounds__(256)
void stats_r(const float* __restrict__ PS, int nb, float* __restrict__ STATS) {
    constexpr int TC = 2 * C;            // 16 / 64 / 256 — divides 256
    constexpr int NS = 256 / TC;
    __shared__ float acc[256];
    int tid = threadIdx.x;
    int c = tid % TC, sl = tid / TC;
    float s = 0.f;
    for (int b = blockIdx.x * NS + sl; b < nb; b += gridDim.x * NS)
        s += PS[(size_t)b * TC + c];
    acc[tid] = s;
    __syncthreads();
    if (tid < TC) {
        float t = 0.f;
#pragma unroll
        for (int s2 = 0; s2 < NS; ++s2) t += acc[s2 * TC + tid];
        float* dst = (tid < C) ? &STATS[tid] : &STATS[128 + (tid - C)];
        atomicAdd(dst, t);
    }
}

// ---------------- pool3 stage 1: 32 blocks/sample, private LDS, partials ----
__global__ __launch_bounds__(256)
void pool3a(const float* __restrict__ y3, const float* __restrict__ st,
            const float* __restrict__ g, const float* __restrict__ be,
            const float* __restrict__ pos,
            unsigned* __restrict__ PK, float* __restrict__ PC,
            float* __restrict__ PP) {
    __shared__ unsigned lkey[7200];
    __shared__ float lcnt[225];
    __shared__ float lpac[675];
    int tid = threadIdx.x;
    for (int t = tid; t < 7200; t += 256) lkey[t] = ENC_NEGINF;
    if (tid < 225) lcnt[tid] = 0.f;
    for (int t = tid; t < 675; t += 256) lpac[t] = 0.f;
    __syncthreads();
    int bid = blockIdx.x;
    int s = bid >> 5, sb = bid & 31;
    int beg = s * 12500 + sb * 391;
    int end = min(s * 12500 + 12500, beg + 391);
    int c = tid & 31, nl = tid >> 5;
    float2 ss = bn_ss(st, g, be, c, INV_N);
    for (int i = beg + nl; i < end; i += 8) {
        float z = y3[(size_t)i * 32 + c] * ss.x + ss.y;
        float px = pos[i * 3], py = pos[i * 3 + 1];
        int cx = min(max((int)floorf(px / 16.f), 0), 14);
        int cy = min(max((int)floorf(py / 12.f), 0), 14);
        int cl = cy * 15 + cx;
        atomicMax(&lkey[cl * 32 + c], enc_f(z));
        if (c == 0) {
            atomicAdd(&lcnt[cl], 1.f);
            atomicAdd(&lpac[cl * 3 + 0], px);
            atomicAdd(&lpac[cl * 3 + 1], py);
            atomicAdd(&lpac[cl * 3 + 2], pos[i * 3 + 2]);
        }
    }
    __syncthreads();
    for (int t = tid; t < 7200; t += 256) PK[(size_t)bid * 7200 + t] = lkey[t];
    if (tid < 225) PC[bid * 225 + tid] = lcnt[tid];
    for (int t = tid; t < 675; t += 256) PP[bid * 675 + t] = lpac[t];
}

// ---------------- pool3 stage 2: reduce 32 partials -> X2, POS2 -------------
__global__ void pool3b(const unsigned* __restrict__ PK, const float* __restrict__ PC,
                       const float* __restrict__ PP,
                       float* __restrict__ X2, float* __restrict__ POS2) {
    int idx = blockIdx.x * blockDim.x + threadIdx.x;
    if (idx < 57600) {
        int s = idx / 7200, t = idx % 7200;
        unsigned m = ENC_NEGINF;
#pragma unroll 8
        for (int sb = 0; sb < 32; ++sb)
            m = max(m, PK[(size_t)(s * 32 + sb) * 7200 + t]);
        X2[idx] = (m == ENC_NEGINF) ? 0.f : dec_f(m);
    } else if (idx < 63000) {
        int j = idx - 57600;
        int s = j / 675, r = j % 675;
        int cl = r / 3;
        float sp = 0.f, sc = 0.f;
#pragma unroll 8
        for (int sb = 0; sb < 32; ++sb) {
            sp += PP[(s * 32 + sb) * 675 + r];
            sc += PC[(s * 32 + sb) * 225 + cl];
        }
        POS2[j] = sp / fmaxf(sc, 1.f);
    }
}

// ---------------- pool5: one block per sample, LDS max, direct store --------
__global__ __launch_bounds__(1024)
void pool5_k(const float* __restrict__ y5, const float* __restrict__ st,
             const float* __restrict__ g, const float* __restrict__ be,
             const float* __restrict__ POS2, float* __restrict__ POOLED) {
    __shared__ unsigned lkey[2048];   // 16 cells x 128 ch
    int tid = threadIdx.x, s = blockIdx.x;
    for (int t = tid; t < 2048; t += 1024) lkey[t] = ENC_NEGINF;
    __syncthreads();
    int c = tid & 127, nl = tid >> 7;
    float2 ss = bn_ss(st, g, be, c, INV_N2);
    for (int j = nl; j < 225; j += 8) {
        int i = s * 225 + j;
        float z = y5[(size_t)i * 128 + c] * ss.x + ss.y;
        float px = POS2[i * 3], py = POS2[i * 3 + 1];
        int cx = min(max((int)floorf(px / 60.f), 0), 3);
        int cy = min(max((int)floorf(py / 45.f), 0), 3);
        atomicMax(&lkey[(cy * 4 + cx) * 128 + c], enc_f(z));
    }
    __syncthreads();
    for (int t = tid; t < 2048; t += 1024) {
        unsigned k = lkey[t];
        POOLED[s * 2048 + t] = (k == ENC_NEGINF) ? 0.f : dec_f(k);
    }
}

// ---------------- FC: 128 blocks = (8 samples x 16 k-chunks), coalesced -----
__global__ __launch_bounds__(256)
void fc_k(const float* __restrict__ POOLED, const float* __restrict__ wfc,
          float* __restrict__ out) {
    __shared__ float row[128];
    __shared__ float acc[256];
    int s = blockIdx.x, kc = blockIdx.y;
    int k0 = kc * 128;
    int tid = threadIdx.x;
    if (tid < 128) row[tid] = POOLED[s * 2048 + k0 + tid];
    __syncthreads();
    int o = tid & 127, half = tid >> 7;
    float a = 0.f;
    if (o < 101) {
        int kk0 = half * 64;
        for (int kk = kk0; kk < kk0 + 64; ++kk)
            a += row[kk] * wfc[(size_t)(k0 + kk) * 101 + o];   // lanes coalesced over o
    }
    acc[tid] = a;
    __syncthreads();
    if (tid < 128 && o < 101)
        atomicAdd(&out[s * 101 + o], acc[tid] + acc[tid + 128]);
}

extern "C" void kernel_launch(void* const* d_in, const int* in_sizes, int n_in,
                              void* d_out, int out_size, void* d_ws, size_t ws_size,
                              hipStream_t stream) {
    const float* x     = (const float*)d_in[0];
    const float* pos   = (const float*)d_in[1];
    const int*   e1    = (const int*)d_in[3];
    const int*   e2    = (const int*)d_in[4];
    const float* w_fc  = (const float*)d_in[40];
    auto WL = [&](int l) { return (const float*)d_in[5 + l * 7 + 0]; };
    auto WS = [&](int l) { return (const float*)d_in[5 + l * 7 + 1]; };
    auto WP = [&](int l) { return (const float*)d_in[5 + l * 7 + 3]; };
    auto BP = [&](int l) { return (const float*)d_in[5 + l * 7 + 4]; };
    auto G_ = [&](int l) { return (const float*)d_in[5 + l * 7 + 5]; };
    auto BE = [&](int l) { return (const float*)d_in[5 + l * 7 + 6]; };

    float* W = (float*)d_ws;
    size_t o = 0;
    float4* SHPf = (float4*)W;        o += 6400000;  // N*16 floats (L1..L3)
    float2* CAPf = (float2*)(W + o);  o += 3200000;
    float*  Y1   = W + o;             o += 800000;
    float*  Y2   = W + o;             o += 800000;
    float*  Z1   = W + o;             o += 800000;
    float*  Y3   = W + o;             o += 3200000;
    float*  STATS = W + o;            o += 5 * 256;
    float*  X2   = W + o;             o += 57600;
    float*  POS2 = W + o;             o += 5400;
    float4* SHPc = (float4*)(W + o);  o += 460800;   // 1800*64 float4
    float2* CAPc = (float2*)(W + o);  o += 230400;
    float*  Y4   = W + o;             o += 57600;
    float*  Y5   = W + o;             o += 230400;
    float*  POOLED = W + o;           o += 16384;
    float*  PSTAT  = W + o;           o += 400000;   // max 6250 blocks * 64
    // pool3 partials alias the (dead after E3) SHPf region:
    unsigned* PK = (unsigned*)W;                  // 256*7200 u32
    float*    PC = W + 2000000;                   // 256*225
    float*    PP = W + 2100000;                   // 256*675

    hipLaunchKernelGGL(init_k, dim3(2), dim3(1024), 0, stream, STATS, (float*)d_out);

    // ---- L1 (1->8) fine ----
    hipLaunchKernelGGL((pass_a<1, 8, 0>), dim3(1563), dim3(256), 0, stream,
                       x, nullptr, nullptr, nullptr, 0.f, nullptr,
                       WL(0), WS(0), WP(0), BP(0), pos,
                       SHPf, CAPf, nullptr, NN_FINE);
    hipLaunchKernelGGL((edge_pass<8, false>), dim3(1563), dim3(256), 0, stream,
                       SHPf, CAPf, e1, (float2*)Y1, PSTAT, NN_FINE);
    hipLaunchKernelGGL((stats_r<8>), dim3(32), dim3(256), 0, stream,
                       PSTAT, 1563, STATS + 0);

    // ---- L2 (8->8) fine, writes Z1=bn(Y1) ----
    hipLaunchKernelGGL((pass_a<8, 8, 1>), dim3(1563), dim3(256), 0, stream,
                       Y1, STATS + 0, G_(0), BE(0), INV_N, nullptr,
                       WL(1), WS(1), WP(1), BP(1), pos,
                       SHPf, CAPf, Z1, NN_FINE);
    hipLaunchKernelGGL((edge_pass<8, false>), dim3(1563), dim3(256), 0, stream,
                       SHPf, CAPf, e1, (float2*)Y2, PSTAT, NN_FINE);
    hipLaunchKernelGGL((stats_r<8>), dim3(32), dim3(256), 0, stream,
                       PSTAT, 1563, STATS + 256);

    // ---- L3 (8->32) fine, f = bn(Y2)+Z1 ----
    hipLaunchKernelGGL((pass_a<8, 32, 2>), dim3(6250), dim3(256), 0, stream,
                       Y2, STATS + 256, G_(1), BE(1), INV_N, Z1,
                       WL(2), WS(2), WP(2), BP(2), pos,
                       SHPf, CAPf, nullptr, NN_FINE);
    hipLaunchKernelGGL((edge_pass<32, false>), dim3(6250), dim3(256), 0, stream,
                       SHPf, CAPf, e1, (float2*)Y3, PSTAT, NN_FINE);
    hipLaunchKernelGGL((stats_r<32>), dim3(32), dim3(256), 0, stream,
                       PSTAT, 6250, STATS + 512);

    // ---- pool3: two-stage (SHPf region is dead now; partials alias it) ----
    hipLaunchKernelGGL(pool3a, dim3(256), dim3(256), 0, stream,
                       Y3, STATS + 512, G_(2), BE(2), pos, PK, PC, PP);
    hipLaunchKernelGGL(pool3b, dim3(247), dim3(256), 0, stream,
                       PK, PC, PP, X2, POS2);

    // ---- L4 (32->32) coarse ----
    hipLaunchKernelGGL((pass_a<32, 32, 0>), dim3(113), dim3(256), 0, stream,
                       X2, nullptr, nullptr, nullptr, 0.f, nullptr,
                       WL(3), WS(3), WP(3), BP(3), POS2,
                       SHPc, CAPc, nullptr, NN_COARSE);
    hipLaunchKernelGGL((edge_pass<32, true>), dim3(113), dim3(256), 0, stream,
                       SHPc, CAPc, e2, (float2*)Y4, PSTAT, NN_COARSE);
    hipLaunchKernelGGL((stats_r<32>), dim3(16), dim3(256), 0, stream,
                       PSTAT, 113, STATS + 768);

    // ---- L5 (32->128) coarse, f = bn(Y4)+X2 ----
    hipLaunchKernelGGL((pass_a<32, 128, 2>), dim3(450), dim3(256), 0, stream,
                       Y4, STATS + 768, G_(3), BE(3), INV_N2, X2,
                       WL(4), WS(4), WP(4), BP(4), POS2,
                       SHPc, CAPc, nullptr, NN_COARSE);
    hipLaunchKernelGGL((edge_pass<128, true>), dim3(450), dim3(256), 0, stream,
                       SHPc, CAPc, e2, (float2*)Y5, PSTAT, NN_COARSE);
    hipLaunchKernelGGL((stats_r<128>), dim3(16), dim3(256), 0, stream,
                       PSTAT, 450, STATS + 1024);

    // ---- pool5 + FC ----
    hipLaunchKernelGGL(pool5_k, dim3(8), dim3(1024), 0, stream,
                       Y5, STATS + 1024, G_(4), BE(4), POS2, POOLED);
    hipLaunchKernelGGL(fc_k, dim3(8, 16), dim3(256), 0, stream,
                       POOLED, w_fc, (float*)d_out);
}